// Round 7
// baseline (567.766 us; speedup 1.0000x reference)
//
#include <hip/hip_runtime.h>
#include <hip/hip_bf16.h>

typedef short bf16x8_t __attribute__((ext_vector_type(8)));
typedef float f32x4_t __attribute__((ext_vector_type(4)));

#define SDIM 2048
#define DDIM 64
#define KBLK 64
#define NKB  (SDIM / KBLK)
#define NBH  48

__device__ __forceinline__ unsigned short f2bf(float f) {
    return __builtin_bit_cast(unsigned short, (__bf16)f);
}
__device__ __forceinline__ unsigned int pack2(float lo, float hi) {
    return ((unsigned int)f2bf(hi) << 16) | (unsigned int)f2bf(lo);
}
__device__ __forceinline__ bf16x8_t pack8(f32x4_t a, f32x4_t b) {
    bf16x8_t r;
    r[0] = (short)f2bf(a[0]); r[1] = (short)f2bf(a[1]);
    r[2] = (short)f2bf(a[2]); r[3] = (short)f2bf(a[3]);
    r[4] = (short)f2bf(b[0]); r[5] = (short)f2bf(b[1]);
    r[6] = (short)f2bf(b[2]); r[7] = (short)f2bf(b[3]);
    return r;
}
__device__ __forceinline__ bf16x8_t pack8s(f32x4_t a, f32x4_t b, float s) {
    bf16x8_t r;
    r[0] = (short)f2bf(a[0] * s); r[1] = (short)f2bf(a[1] * s);
    r[2] = (short)f2bf(a[2] * s); r[3] = (short)f2bf(a[3] * s);
    r[4] = (short)f2bf(b[0] * s); r[5] = (short)f2bf(b[1] * s);
    r[6] = (short)f2bf(b[2] * s); r[7] = (short)f2bf(b[3] * s);
    return r;
}
struct uint4s { unsigned int x, y, z, w; };

// ---------- prep 1: K fp32 -> bf16 (row-major) ----------
__global__ __launch_bounds__(256) void cvt_k_kernel(const float* __restrict__ K,
                                                    unsigned short* __restrict__ Kb) {
    size_t i = ((size_t)blockIdx.x * 256 + threadIdx.x) * 8;
    f32x4_t a = *(const f32x4_t*)(K + i);
    f32x4_t b = *(const f32x4_t*)(K + i + 4);
    *(bf16x8_t*)(Kb + i) = pack8(a, b);
}

// ---------- prep 2: V fp32 [bh][k][d] -> bf16 V^T [bh][d][k] ----------
__global__ __launch_bounds__(256) void tr_v_kernel(const float* __restrict__ V,
                                                   unsigned short* __restrict__ VT) {
    __shared__ unsigned short lt[64 * 72];
    const int bh = blockIdx.x >> 5;
    const int kt = blockIdx.x & 31;
    const float* Vb = V + (size_t)bh * (SDIM * DDIM) + (size_t)kt * 64 * DDIM;
    unsigned short* VTb = VT + (size_t)bh * (DDIM * SDIM) + kt * 64;
    const int t = threadIdx.x;
    {
        const int kl = t >> 2, dg = t & 3;
        const float* vp = Vb + kl * DDIM + dg * 16;
        f32x4_t v0 = *(const f32x4_t*)vp;
        f32x4_t v1 = *(const f32x4_t*)(vp + 4);
        f32x4_t v2 = *(const f32x4_t*)(vp + 8);
        f32x4_t v3 = *(const f32x4_t*)(vp + 12);
#pragma unroll
        for (int j = 0; j < 16; ++j) {
            float f = (j < 4) ? v0[j] : (j < 8) ? v1[j - 4] : (j < 12) ? v2[j - 8] : v3[j - 12];
            lt[(dg * 16 + j) * 72 + kl] = f2bf(f);
        }
    }
    __syncthreads();
    {
        const int d = t >> 2, kg = t & 3;
        bf16x8_t w0 = *(const bf16x8_t*)&lt[d * 72 + kg * 16];
        bf16x8_t w1 = *(const bf16x8_t*)&lt[d * 72 + kg * 16 + 8];
        *(bf16x8_t*)(VTb + (size_t)d * SDIM + kg * 16) = w0;
        *(bf16x8_t*)(VTb + (size_t)d * SDIM + kg * 16 + 8) = w1;
    }
}

// ---------- main: swapped QK^T, shfl-based P redistribution, NO LDS ----------
__global__ __launch_bounds__(256, 3) void sdpa_main_kernel(
    const float* __restrict__ Q, const unsigned short* __restrict__ Kb,
    const unsigned short* __restrict__ VT, float* __restrict__ out,
    float* __restrict__ attn)
{
    const int bid = blockIdx.x;
    const int bh  = bid >> 5;
    const int qt  = bid & 31;
    const int tid = threadIdx.x;
    const int lane = tid & 63;
    const int wv   = tid >> 6;     // 0..3
    const int l15  = lane & 15;    // this lane's q-row (swapped layout)
    const int hi   = lane >> 4;    // 0..3
    const int qbase = qt * 64 + wv * 16;

    const unsigned short* KbB = Kb + (size_t)bh * (SDIM * DDIM);
    const unsigned short* VTb = VT + (size_t)bh * (DDIM * SDIM);
    float* outW  = out  + ((size_t)bh * SDIM + qbase) * DDIM;
    float* attnW = attn + (size_t)bh * SDIM * SDIM + (size_t)qbase * SDIM;

    const float SC = 0.18033688011112042f;  // (1/sqrt(64)) * log2(e)

    // ---- Q fragment (B operand), pre-scaled by SC
    const float* qp = Q + ((size_t)bh * SDIM + qbase + l15) * DDIM + hi * 8;
    const bf16x8_t aq0 = pack8s(*(const f32x4_t*)qp,        *(const f32x4_t*)(qp + 4), SC);
    const bf16x8_t aq1 = pack8s(*(const f32x4_t*)(qp + 32), *(const f32x4_t*)(qp + 36), SC);

    // ================= pass A: row sums (lane-local q) =================
    float rs = 0.f;
    {
        const unsigned short* kp0 = KbB + (size_t)l15 * DDIM + hi * 8;
        bf16x8_t cur[8];
#pragma unroll
        for (int s = 0; s < 4; ++s) {
            cur[s * 2]     = *(const bf16x8_t*)(kp0 + (size_t)(s * 16) * DDIM);
            cur[s * 2 + 1] = *(const bf16x8_t*)(kp0 + (size_t)(s * 16) * DDIM + 32);
        }
        for (int ci = 0; ci < NKB; ++ci) {
            bf16x8_t nxt[8];
#pragma unroll
            for (int s = 0; s < 8; ++s) nxt[s] = cur[s];
            if (ci < NKB - 1) {
                const unsigned short* np = kp0 + (size_t)(ci + 1) * KBLK * DDIM;
#pragma unroll
                for (int s = 0; s < 4; ++s) {
                    nxt[s * 2]     = *(const bf16x8_t*)(np + (size_t)(s * 16) * DDIM);
                    nxt[s * 2 + 1] = *(const bf16x8_t*)(np + (size_t)(s * 16) * DDIM + 32);
                }
            }
#pragma unroll
            for (int s = 0; s < 4; ++s) {
                f32x4_t acc = {0.f, 0.f, 0.f, 0.f};
                acc = __builtin_amdgcn_mfma_f32_16x16x32_bf16(cur[s * 2],     aq0, acc, 0, 0, 0);
                acc = __builtin_amdgcn_mfma_f32_16x16x32_bf16(cur[s * 2 + 1], aq1, acc, 0, 0, 0);
                rs += __builtin_amdgcn_exp2f(acc[0]) + __builtin_amdgcn_exp2f(acc[1])
                    + __builtin_amdgcn_exp2f(acc[2]) + __builtin_amdgcn_exp2f(acc[3]);
            }
#pragma unroll
            for (int s = 0; s < 8; ++s) cur[s] = nxt[s];
        }
    }
    rs += __shfl_xor(rs, 16);
    rs += __shfl_xor(rs, 32);
    const float nlg = __builtin_amdgcn_logf(rs);  // log2 of row sum (lane-local q)

    // ================= pass B =================
    f32x4_t oacc[4] = {{0.f,0.f,0.f,0.f},{0.f,0.f,0.f,0.f},{0.f,0.f,0.f,0.f},{0.f,0.f,0.f,0.f}};
    f32x4_t pprev[4];

    // shfl source lanes for the P redistribution (constant per thread)
    const int laneA = l15 + ((hi & 1) << 5);  // hi' = (hi&1)*2
    const int laneB = laneA + 16;             // hi' = (hi&1)*2 + 1
    const bool selHi = (hi >> 1) != 0;        // s-group parity this lane consumes

    for (int kb = 0; kb < NKB; ++kb) {
        const int kbase = kb * KBLK;

        // --- phase 0: issue ALL loads for this iter (oldest in vmcnt FIFO)
        bf16x8_t kc[8];
        {
            const unsigned short* kp = KbB + (size_t)(kbase + l15) * DDIM + hi * 8;
#pragma unroll
            for (int s = 0; s < 4; ++s) {
                kc[s * 2]     = *(const bf16x8_t*)(kp + (size_t)(s * 16) * DDIM);
                kc[s * 2 + 1] = *(const bf16x8_t*)(kp + (size_t)(s * 16) * DDIM + 32);
            }
        }
        bf16x8_t vv[8];
        {
            const unsigned short* vp = VTb + (size_t)l15 * SDIM + kbase + hi * 8;
#pragma unroll
            for (int dt = 0; dt < 4; ++dt) {
                vv[dt * 2]     = *(const bf16x8_t*)(vp + (size_t)(dt * 16) * SDIM);
                vv[dt * 2 + 1] = *(const bf16x8_t*)(vp + (size_t)(dt * 16) * SDIM + 32);
            }
        }

        // --- phase 0.5: attn stores for kb-1 (newest VMEM -> never gate waits)
        if (kb > 0) {
            float* ap = attnW + (size_t)l15 * SDIM + (kbase - KBLK) + hi * 4;
#pragma unroll
            for (int s = 0; s < 4; ++s)
                __builtin_nontemporal_store(pprev[s], (f32x4_t*)(ap + s * 16));
        }

        // --- phase 1: QK^T (swapped: D rows = keys, cols = q)
        f32x4_t acc[4];
        __builtin_amdgcn_s_setprio(1);
#pragma unroll
        for (int s = 0; s < 4; ++s) {
            f32x4_t a = {0.f, 0.f, 0.f, 0.f};
            a = __builtin_amdgcn_mfma_f32_16x16x32_bf16(kc[s * 2],     aq0, a, 0, 0, 0);
            a = __builtin_amdgcn_mfma_f32_16x16x32_bf16(kc[s * 2 + 1], aq1, a, 0, 0, 0);
            acc[s] = a;
        }
        __builtin_amdgcn_s_setprio(0);

        // --- phase 2: softmax -> normalized p (f32, lane-local q-row)
        f32x4_t p[4];
#pragma unroll
        for (int s = 0; s < 4; ++s) {
#pragma unroll
            for (int r = 0; r < 4; ++r)
                p[s][r] = __builtin_amdgcn_exp2f(acc[s][r] - nlg);
        }

        // --- phase 3: pack p to bf16 pairs (keys s*16+hi*4+{0,1} / {2,3})
        unsigned int w0[4], w1[4];
#pragma unroll
        for (int s = 0; s < 4; ++s) {
            w0[s] = pack2(p[s][0], p[s][1]);
            w1[s] = pack2(p[s][2], p[s][3]);
        }

        // --- phase 4: shfl redistribution -> PV A-fragments
        // af[k2] word m = w[m&1] of s=2k2+(hi>>1), from lane l15+32*(hi&1)+16*(m>>1)
        bf16x8_t af[2];
#pragma unroll
        for (int k2 = 0; k2 < 2; ++k2) {
            const int sL = 2 * k2, sH = 2 * k2 + 1;
            unsigned int W0a = (unsigned int)__shfl((int)w0[sL], laneA);
            unsigned int W0b = (unsigned int)__shfl((int)w0[sH], laneA);
            unsigned int W1a = (unsigned int)__shfl((int)w1[sL], laneA);
            unsigned int W1b = (unsigned int)__shfl((int)w1[sH], laneA);
            unsigned int W2a = (unsigned int)__shfl((int)w0[sL], laneB);
            unsigned int W2b = (unsigned int)__shfl((int)w0[sH], laneB);
            unsigned int W3a = (unsigned int)__shfl((int)w1[sL], laneB);
            unsigned int W3b = (unsigned int)__shfl((int)w1[sH], laneB);
            uint4s W;
            W.x = selHi ? W0b : W0a;
            W.y = selHi ? W1b : W1a;
            W.z = selHi ? W2b : W2a;
            W.w = selHi ? W3b : W3a;
            af[k2] = __builtin_bit_cast(bf16x8_t, W);
        }

        // --- phase 5: PV
        __builtin_amdgcn_s_setprio(1);
#pragma unroll
        for (int dt = 0; dt < 4; ++dt) {
            oacc[dt] = __builtin_amdgcn_mfma_f32_16x16x32_bf16(af[0], vv[dt * 2],     oacc[dt], 0, 0, 0);
            oacc[dt] = __builtin_amdgcn_mfma_f32_16x16x32_bf16(af[1], vv[dt * 2 + 1], oacc[dt], 0, 0, 0);
        }
        __builtin_amdgcn_s_setprio(0);

#pragma unroll
        for (int s = 0; s < 4; ++s) pprev[s] = p[s];
    }
    // --- final attn stores
    {
        float* ap = attnW + (size_t)l15 * SDIM + (SDIM - KBLK) + hi * 4;
#pragma unroll
        for (int s = 0; s < 4; ++s)
            __builtin_nontemporal_store(pprev[s], (f32x4_t*)(ap + s * 16));
    }

    // --- epilogue: output (normalized)
#pragma unroll
    for (int dt = 0; dt < 4; ++dt) {
#pragma unroll
        for (int r = 0; r < 4; ++r)
            outW[(size_t)(hi * 4 + r) * DDIM + dt * 16 + l15] = oacc[dt][r];
    }
}

extern "C" void kernel_launch(void* const* d_in, const int* in_sizes, int n_in,
                              void* d_out, int out_size, void* d_ws, size_t ws_size,
                              hipStream_t stream) {
    const float* Q = (const float*)d_in[0];
    const float* K = (const float*)d_in[1];
    const float* V = (const float*)d_in[2];
    float* out  = (float*)d_out;
    float* attn = out + (size_t)NBH * SDIM * DDIM;

    unsigned short* Kb = (unsigned short*)d_ws;
    unsigned short* VT = Kb + (size_t)NBH * SDIM * DDIM;

    cvt_k_kernel<<<dim3((NBH * SDIM * DDIM) / (256 * 8)), dim3(256), 0, stream>>>(K, Kb);
    tr_v_kernel<<<dim3(NBH * 32), dim3(256), 0, stream>>>(V, VT);

    sdpa_main_kernel<<<dim3(NBH * 32), dim3(256), 0, stream>>>(Q, Kb, VT, out, attn);
}